// Round 2
// baseline (1261.883 us; speedup 1.0000x reference)
//
#include <hip/hip_runtime.h>

// Problem constants (fixed by the reference file).
#define D_DIM    512
#define B_DIM    64        // == wave width: lane l accumulates segment l
#define L_DIM    2048
#define NBLK1    256
#define THREADS1 512       // 8 waves; wave w owns columns [64w, 64w+64)
#define MAXCHUNK 512

// ---------------------------------------------------------------------------
// Phase 1: segment-sum with lane==segment register accumulation.
// Wave w of each block owns a 64-column slice; lane l holds x[l, 64w+j] for
// j in [0,64) in 64 VGPRs. Per node: one coalesced 256 B load, per-lane
// weight w = (l==p0)+(l==p1), then 64 x (v_readlane + v_fmac). No LDS RMW,
// no atomics, no dependent memory chains in the hot loop.
// ---------------------------------------------------------------------------
__global__ __launch_bounds__(THREADS1)
void seg_sum_lane(const float* __restrict__ g, const int* __restrict__ tp,
                  float* __restrict__ x, int N, int chunk) {
    __shared__ int pos[2 * MAXCHUNK];      // 4 KiB staged positions
    const int tid  = threadIdx.x;
    const int wave = tid >> 6;             // 0..7 -> column group
    const int lane = tid & 63;             // == segment id

    int start = blockIdx.x * chunk;
    int end   = start + chunk; if (end > N) end = N;
    int n     = end - start;

    for (int i = tid; i < 2 * n; i += THREADS1) pos[i] = tp[2 * start + i];
    __syncthreads();

    float acc[64];
    #pragma unroll
    for (int j = 0; j < 64; ++j) acc[j] = 0.0f;

    const float* gp = g + (size_t)start * D_DIM + wave * 64 + lane;

    int i = 0;
    for (; i + 4 <= n; i += 4) {
        // 4 independent 256 B loads in flight per wave.
        float v0 = gp[(size_t)(i + 0) * D_DIM];
        float v1 = gp[(size_t)(i + 1) * D_DIM];
        float v2 = gp[(size_t)(i + 2) * D_DIM];
        float v3 = gp[(size_t)(i + 3) * D_DIM];
        int p0a = pos[2*i+0], p0b = pos[2*i+1];
        int p1a = pos[2*i+2], p1b = pos[2*i+3];
        int p2a = pos[2*i+4], p2b = pos[2*i+5];
        int p3a = pos[2*i+6], p3b = pos[2*i+7];
        float w0 = (float)((lane == p0a) + (lane == p0b));
        float w1 = (float)((lane == p1a) + (lane == p1b));
        float w2 = (float)((lane == p2a) + (lane == p2b));
        float w3 = (float)((lane == p3a) + (lane == p3b));
        int i0 = __float_as_int(v0), i1 = __float_as_int(v1);
        int i2 = __float_as_int(v2), i3 = __float_as_int(v3);
        #pragma unroll
        for (int j = 0; j < 64; ++j) {
            acc[j] += __int_as_float(__builtin_amdgcn_readlane(i0, j)) * w0;
            acc[j] += __int_as_float(__builtin_amdgcn_readlane(i1, j)) * w1;
            acc[j] += __int_as_float(__builtin_amdgcn_readlane(i2, j)) * w2;
            acc[j] += __int_as_float(__builtin_amdgcn_readlane(i3, j)) * w3;
        }
    }
    for (; i < n; ++i) {
        float v = gp[(size_t)i * D_DIM];
        int pa = pos[2*i+0], pb = pos[2*i+1];
        float w = (float)((lane == pa) + (lane == pb));
        int vi = __float_as_int(v);
        #pragma unroll
        for (int j = 0; j < 64; ++j)
            acc[j] += __int_as_float(__builtin_amdgcn_readlane(vi, j)) * w;
    }

    // Flush: lane l holds row l, columns wave*64 + j. 64 global atomics/thread.
    float* xrow = x + (size_t)lane * D_DIM + wave * 64;
    #pragma unroll
    for (int j = 0; j < 64; ++j) {
        if (acc[j] != 0.0f) atomicAdd(&xrow[j], acc[j]);
    }
}

// ---------------------------------------------------------------------------
// Phase 2: broadcast x [B, D] -> out [B, L, D] as a purely linear store
// stream. idx -> (b = idx>>18, d4 = idx&127); all pow-2 arithmetic.
// ---------------------------------------------------------------------------
#define BCAST_BLOCKS 4096
#define THREADS2     256
__global__ __launch_bounds__(THREADS2)
void bcast2(const float4* __restrict__ x4, float4* __restrict__ out) {
    const size_t total  = (size_t)B_DIM * L_DIM * (D_DIM / 4);  // 16,777,216
    const size_t stride = (size_t)BCAST_BLOCKS * THREADS2;      // 1,048,576
    for (size_t idx = (size_t)blockIdx.x * THREADS2 + threadIdx.x;
         idx < total; idx += stride) {
        int b  = (int)(idx >> 18);        // L*D/4 = 262144 = 2^18
        int d4 = (int)(idx & 127);        // D/4 - 1
        out[idx] = x4[(b << 7) | d4];     // x row resident in L1/L2
    }
}

extern "C" void kernel_launch(void* const* d_in, const int* in_sizes, int n_in,
                              void* d_out, int out_size, void* d_ws, size_t ws_size,
                              hipStream_t stream) {
    const float* g   = (const float*)d_in[0];
    const int*   tp  = (const int*)d_in[1];
    float*       out = (float*)d_out;
    float*       x   = (float*)d_ws;       // [B, D] accumulator, 128 KiB

    int N = in_sizes[1] / 2;               // 100000
    int chunk = (N + NBLK1 - 1) / NBLK1;   // 391 <= MAXCHUNK

    // d_ws is poisoned 0xAA before every call: zero the accumulator.
    hipMemsetAsync(d_ws, 0, B_DIM * D_DIM * sizeof(float), stream);

    seg_sum_lane<<<NBLK1, THREADS1, 0, stream>>>(g, tp, x, N, chunk);
    bcast2<<<BCAST_BLOCKS, THREADS2, 0, stream>>>((const float4*)x, (float4*)out);
}

// Round 4
// 863.923 us; speedup vs baseline: 1.4606x; 1.4606x over previous
//
#include <hip/hip_runtime.h>

// Problem constants (fixed by the reference file).
#define D_DIM    512
#define B_DIM    64
#define L_DIM    2048
#define NBLK1    256       // phase-1 blocks; 1/CU (132 KiB LDS)
#define THREADS1 512
#define MAXCHUNK 512
#define XSZ      (B_DIM * D_DIM)          // 32768 floats per partial

// Native clang vector type: required by __builtin_nontemporal_store
// (HIP_vector_type float4 is a struct and is rejected).
typedef float f32x4 __attribute__((ext_vector_type(4)));

// ---------------------------------------------------------------------------
// Phase 1: per-block segment-sum into a [B, D] LDS accumulator (thread t owns
// column t; ds_add_f32 breaks the compiler's RMW dep chain on dynamic LDS
// indices). Flush is PLAIN float4 stores to a per-block partial in d_ws --
// R1's 8.4M same-address global atomics are gone (theory: they were ~450 us
// of serialized L2 RMW). Fallback path (use_atomic=1) keeps R1 semantics if
// ws is too small.
// ---------------------------------------------------------------------------
__global__ __launch_bounds__(THREADS1)
void seg_sum_kernel(const float* __restrict__ g, const int* __restrict__ tp,
                    float* __restrict__ dst, int N, int chunk, int use_atomic) {
    __shared__ float acc[XSZ];             // 128 KiB
    __shared__ int   pos[2 * MAXCHUNK];    // 4 KiB
    const int tid = threadIdx.x;

    for (int i = tid; i < XSZ; i += THREADS1) acc[i] = 0.0f;

    int start = blockIdx.x * chunk;
    int end   = start + chunk; if (end > N) end = N;
    int n     = end - start;
    for (int i = tid; i < 2 * n; i += THREADS1) pos[i] = tp[2 * start + i];
    __syncthreads();

    const float* gp = g + (size_t)start * D_DIM + tid;

    int i = 0;
    for (; i + 8 <= n; i += 8) {
        // 8 independent 256 B loads in flight per wave (16 KB/CU at 8 waves).
        float v0 = gp[(size_t)(i + 0) * D_DIM];
        float v1 = gp[(size_t)(i + 1) * D_DIM];
        float v2 = gp[(size_t)(i + 2) * D_DIM];
        float v3 = gp[(size_t)(i + 3) * D_DIM];
        float v4 = gp[(size_t)(i + 4) * D_DIM];
        float v5 = gp[(size_t)(i + 5) * D_DIM];
        float v6 = gp[(size_t)(i + 6) * D_DIM];
        float v7 = gp[(size_t)(i + 7) * D_DIM];
        atomicAdd(&acc[pos[2*i+ 0] * D_DIM + tid], v0);
        atomicAdd(&acc[pos[2*i+ 1] * D_DIM + tid], v0);
        atomicAdd(&acc[pos[2*i+ 2] * D_DIM + tid], v1);
        atomicAdd(&acc[pos[2*i+ 3] * D_DIM + tid], v1);
        atomicAdd(&acc[pos[2*i+ 4] * D_DIM + tid], v2);
        atomicAdd(&acc[pos[2*i+ 5] * D_DIM + tid], v2);
        atomicAdd(&acc[pos[2*i+ 6] * D_DIM + tid], v3);
        atomicAdd(&acc[pos[2*i+ 7] * D_DIM + tid], v3);
        atomicAdd(&acc[pos[2*i+ 8] * D_DIM + tid], v4);
        atomicAdd(&acc[pos[2*i+ 9] * D_DIM + tid], v4);
        atomicAdd(&acc[pos[2*i+10] * D_DIM + tid], v5);
        atomicAdd(&acc[pos[2*i+11] * D_DIM + tid], v5);
        atomicAdd(&acc[pos[2*i+12] * D_DIM + tid], v6);
        atomicAdd(&acc[pos[2*i+13] * D_DIM + tid], v6);
        atomicAdd(&acc[pos[2*i+14] * D_DIM + tid], v7);
        atomicAdd(&acc[pos[2*i+15] * D_DIM + tid], v7);
    }
    for (; i < n; ++i) {
        float v = gp[(size_t)i * D_DIM];
        atomicAdd(&acc[pos[2*i + 0] * D_DIM + tid], v);
        atomicAdd(&acc[pos[2*i + 1] * D_DIM + tid], v);
    }
    __syncthreads();

    if (use_atomic) {
        for (int j = tid; j < XSZ; j += THREADS1) {
            float v = acc[j];
            if (v != 0.0f) atomicAdd(&dst[j], v);
        }
    } else {
        // Plain coalesced float4 stores of this block's partial.
        f32x4* outp = (f32x4*)(dst + (size_t)blockIdx.x * XSZ);
        const f32x4* a4 = (const f32x4*)acc;
        for (int j = tid; j < XSZ / 4; j += THREADS1) outp[j] = a4[j];
    }
}

// ---------------------------------------------------------------------------
// Reduce 256 per-block partials -> x [B, D]. 33.6 MB of reads, mostly L2.
// ---------------------------------------------------------------------------
__global__ __launch_bounds__(128)
void reduce_partials(const float* __restrict__ p, float* __restrict__ x) {
    int j = blockIdx.x * 128 + threadIdx.x;     // 0..32767
    const float* pj = p + j;
    float s = 0.0f;
    #pragma unroll 8
    for (int k = 0; k < NBLK1; ++k) s += pj[(size_t)k * XSZ];
    x[j] = s;
}

// ---------------------------------------------------------------------------
// Phase 2: broadcast x [B, D] -> out [B, L, D]. Nontemporal float4 stores to
// bypass L2 allocation on the 268 MB stream (theory: L2 write-allocate capped
// R1/R2 bcast at ~0.8 TB/s).
// ---------------------------------------------------------------------------
#define LTILE    128
#define THREADS2 256
__global__ __launch_bounds__(THREADS2)
void bcast_nt(const float* __restrict__ x, f32x4* __restrict__ out) {
    const int tiles_per_b = L_DIM / LTILE;                // 16
    int b     = blockIdx.x / tiles_per_b;
    int ltile = blockIdx.x % tiles_per_b;
    int d4    = threadIdx.x & (D_DIM / 4 - 1);            // 0..127
    int lo    = threadIdx.x >> 7;                         // 0..1

    const f32x4* x4 = (const f32x4*)x;
    f32x4 v = x4[(b << 7) | d4];

    size_t base = ((size_t)b * L_DIM + (size_t)ltile * LTILE) * (D_DIM / 4) + d4;
    #pragma unroll 8
    for (int l = lo; l < LTILE; l += 2) {
        __builtin_nontemporal_store(v, &out[base + (size_t)l * (D_DIM / 4)]);
    }
}

extern "C" void kernel_launch(void* const* d_in, const int* in_sizes, int n_in,
                              void* d_out, int out_size, void* d_ws, size_t ws_size,
                              hipStream_t stream) {
    const float* g   = (const float*)d_in[0];
    const int*   tp  = (const int*)d_in[1];
    float*       out = (float*)d_out;

    int N = in_sizes[1] / 2;               // 100000
    int chunk = (N + NBLK1 - 1) / NBLK1;   // 391 <= MAXCHUNK

    const size_t need = (size_t)(NBLK1 + 1) * XSZ * sizeof(float);  // 33.7 MB

    if (ws_size >= need) {
        float* partials = (float*)d_ws;                    // [256][32768]
        float* x        = partials + (size_t)NBLK1 * XSZ;  // [64][512]
        seg_sum_kernel<<<NBLK1, THREADS1, 0, stream>>>(g, tp, partials, N, chunk, 0);
        reduce_partials<<<XSZ / 128, 128, 0, stream>>>(partials, x);
        bcast_nt<<<B_DIM * (L_DIM / LTILE), THREADS2, 0, stream>>>(x, (f32x4*)out);
    } else {
        // Fallback: atomic flush into x (d_ws poisoned 0xAA -> zero it first).
        float* x = (float*)d_ws;
        (void)hipMemsetAsync(d_ws, 0, XSZ * sizeof(float), stream);
        seg_sum_kernel<<<NBLK1, THREADS1, 0, stream>>>(g, tp, x, N, chunk, 1);
        bcast_nt<<<B_DIM * (L_DIM / LTILE), THREADS2, 0, stream>>>(x, (f32x4*)out);
    }
}

// Round 5
// 856.979 us; speedup vs baseline: 1.4725x; 1.0081x over previous
//
#include <hip/hip_runtime.h>

// Problem constants (fixed by the reference file).
#define D_DIM    512
#define B_DIM    64
#define L_DIM    2048
#define NBLK1    256       // phase-1 blocks; 1/CU (132 KiB LDS)
#define THREADS1 512
#define MAXCHUNK 512
#define XSZ      (B_DIM * D_DIM)          // 32768 floats per partial
#define KSPLIT   4                        // reduce parallelism over partials

// Native clang vector type (required by __builtin_nontemporal_store).
typedef float f32x4 __attribute__((ext_vector_type(4)));

// ---------------------------------------------------------------------------
// Phase 1: per-block segment-sum into a [B, D] LDS accumulator.
// KEY FIX vs R4: unsafeAtomicAdd -> native ds_add_f32 (fire-and-forget,
// pipelined). Plain atomicAdd(float*) on LDS compiles to a CAS loop
// (~200 cyc/op serialized -- matches R4's 525 us @ VALUBusy 0.9%).
// ---------------------------------------------------------------------------
__global__ __launch_bounds__(THREADS1)
void seg_sum_kernel(const float* __restrict__ g, const int* __restrict__ tp,
                    float* __restrict__ dst, int N, int chunk, int use_atomic) {
    __shared__ float acc[XSZ];             // 128 KiB
    __shared__ int   pos[2 * MAXCHUNK];    // 4 KiB
    const int tid = threadIdx.x;

    for (int i = tid; i < XSZ; i += THREADS1) acc[i] = 0.0f;

    int start = blockIdx.x * chunk;
    int end   = start + chunk; if (end > N) end = N;
    int n     = end - start;
    for (int i = tid; i < 2 * n; i += THREADS1) pos[i] = tp[2 * start + i];
    __syncthreads();

    const float* gp = g + (size_t)start * D_DIM + tid;

    int i = 0;
    for (; i + 8 <= n; i += 8) {
        // 8 independent 256 B loads in flight per wave (16 KB/CU at 8 waves).
        float v0 = gp[(size_t)(i + 0) * D_DIM];
        float v1 = gp[(size_t)(i + 1) * D_DIM];
        float v2 = gp[(size_t)(i + 2) * D_DIM];
        float v3 = gp[(size_t)(i + 3) * D_DIM];
        float v4 = gp[(size_t)(i + 4) * D_DIM];
        float v5 = gp[(size_t)(i + 5) * D_DIM];
        float v6 = gp[(size_t)(i + 6) * D_DIM];
        float v7 = gp[(size_t)(i + 7) * D_DIM];
        unsafeAtomicAdd(&acc[pos[2*i+ 0] * D_DIM + tid], v0);
        unsafeAtomicAdd(&acc[pos[2*i+ 1] * D_DIM + tid], v0);
        unsafeAtomicAdd(&acc[pos[2*i+ 2] * D_DIM + tid], v1);
        unsafeAtomicAdd(&acc[pos[2*i+ 3] * D_DIM + tid], v1);
        unsafeAtomicAdd(&acc[pos[2*i+ 4] * D_DIM + tid], v2);
        unsafeAtomicAdd(&acc[pos[2*i+ 5] * D_DIM + tid], v2);
        unsafeAtomicAdd(&acc[pos[2*i+ 6] * D_DIM + tid], v3);
        unsafeAtomicAdd(&acc[pos[2*i+ 7] * D_DIM + tid], v3);
        unsafeAtomicAdd(&acc[pos[2*i+ 8] * D_DIM + tid], v4);
        unsafeAtomicAdd(&acc[pos[2*i+ 9] * D_DIM + tid], v4);
        unsafeAtomicAdd(&acc[pos[2*i+10] * D_DIM + tid], v5);
        unsafeAtomicAdd(&acc[pos[2*i+11] * D_DIM + tid], v5);
        unsafeAtomicAdd(&acc[pos[2*i+12] * D_DIM + tid], v6);
        unsafeAtomicAdd(&acc[pos[2*i+13] * D_DIM + tid], v6);
        unsafeAtomicAdd(&acc[pos[2*i+14] * D_DIM + tid], v7);
        unsafeAtomicAdd(&acc[pos[2*i+15] * D_DIM + tid], v7);
    }
    for (; i < n; ++i) {
        float v = gp[(size_t)i * D_DIM];
        unsafeAtomicAdd(&acc[pos[2*i + 0] * D_DIM + tid], v);
        unsafeAtomicAdd(&acc[pos[2*i + 1] * D_DIM + tid], v);
    }
    __syncthreads();

    if (use_atomic) {
        for (int j = tid; j < XSZ; j += THREADS1) {
            float v = acc[j];
            if (v != 0.0f) unsafeAtomicAdd(&dst[j], v);
        }
    } else {
        // Plain coalesced float4 stores of this block's partial.
        f32x4* outp = (f32x4*)(dst + (size_t)blockIdx.x * XSZ);
        const f32x4* a4 = (const f32x4*)acc;
        for (int j = tid; j < XSZ / 4; j += THREADS1) outp[j] = a4[j];
    }
}

// ---------------------------------------------------------------------------
// Reduce 256 per-block partials -> KSPLIT partial x vectors (summed in bcast).
// 4-way K-split: 1024 blocks instead of 256 -> 4x the in-flight loads.
// ---------------------------------------------------------------------------
__global__ __launch_bounds__(128)
void reduce_partials(const float* __restrict__ p, float* __restrict__ xp) {
    const int jblks = XSZ / 128;                 // 256
    int jblk = blockIdx.x % jblks;
    int ks   = blockIdx.x / jblks;               // 0..KSPLIT-1
    int j    = jblk * 128 + threadIdx.x;
    const float* pj = p + j + (size_t)ks * (NBLK1 / KSPLIT) * XSZ;
    float s = 0.0f;
    #pragma unroll 8
    for (int k = 0; k < NBLK1 / KSPLIT; ++k) s += pj[(size_t)k * XSZ];
    xp[(size_t)ks * XSZ + j] = s;
}

// ---------------------------------------------------------------------------
// Phase 2: broadcast. Each wave owns one CONTIGUOUS 64 KB span of out (4096
// float4s = 32 l-rows of one b) and streams sequential 1 KB wave-stores --
// the most DRAM-friendly store pattern expressible. 1024 blocks x 4 waves =
// 4096 spans. Sums nparts partial x vectors on the way in (8 cached loads).
// ---------------------------------------------------------------------------
#define BC_BLOCKS  1024
#define BC_THREADS 256
__global__ __launch_bounds__(BC_THREADS)
void bcast_lin(const float* __restrict__ xp, int nparts, f32x4* __restrict__ out) {
    int gw   = (blockIdx.x * BC_THREADS + threadIdx.x) >> 6;  // global wave 0..4095
    int lane = threadIdx.x & 63;
    size_t base = (size_t)gw * 4096;          // float4 units; span = 64 KB
    int b = (int)(base >> 18);                // 2^18 float4s per b

    const f32x4* x4 = (const f32x4*)xp;
    f32x4 v0 = x4[(b << 7) | lane];
    f32x4 v1 = x4[(b << 7) | (64 + lane)];
    for (int p = 1; p < nparts; ++p) {
        v0 += x4[(size_t)p * (XSZ / 4) + ((b << 7) | lane)];
        v1 += x4[(size_t)p * (XSZ / 4) + ((b << 7) | (64 + lane))];
    }

    f32x4* o = out + base + lane;
    #pragma unroll 8
    for (int t = 0; t < 64; t += 2) {
        __builtin_nontemporal_store(v0, &o[(size_t)t * 64]);
        __builtin_nontemporal_store(v1, &o[(size_t)t * 64 + 64]);
    }
}

extern "C" void kernel_launch(void* const* d_in, const int* in_sizes, int n_in,
                              void* d_out, int out_size, void* d_ws, size_t ws_size,
                              hipStream_t stream) {
    const float* g   = (const float*)d_in[0];
    const int*   tp  = (const int*)d_in[1];
    float*       out = (float*)d_out;

    int N = in_sizes[1] / 2;               // 100000
    int chunk = (N + NBLK1 - 1) / NBLK1;   // 391 <= MAXCHUNK

    const size_t need = (size_t)(NBLK1 + KSPLIT) * XSZ * sizeof(float);  // 34.1 MB

    if (ws_size >= need) {
        float* partials = (float*)d_ws;                    // [256][32768]
        float* xp       = partials + (size_t)NBLK1 * XSZ;  // [KSPLIT][32768]
        seg_sum_kernel<<<NBLK1, THREADS1, 0, stream>>>(g, tp, partials, N, chunk, 0);
        reduce_partials<<<(XSZ / 128) * KSPLIT, 128, 0, stream>>>(partials, xp);
        bcast_lin<<<BC_BLOCKS, BC_THREADS, 0, stream>>>(xp, KSPLIT, (f32x4*)out);
    } else {
        // Fallback: atomic flush into x (d_ws poisoned 0xAA -> zero it first).
        float* x = (float*)d_ws;
        (void)hipMemsetAsync(d_ws, 0, XSZ * sizeof(float), stream);
        seg_sum_kernel<<<NBLK1, THREADS1, 0, stream>>>(g, tp, x, N, chunk, 1);
        bcast_lin<<<BC_BLOCKS, BC_THREADS, 0, stream>>>(x, 1, (f32x4*)out);
    }
}

// Round 6
// 434.670 us; speedup vs baseline: 2.9031x; 1.9716x over previous
//
#include <hip/hip_runtime.h>

// Problem constants (fixed by the reference file).
#define D_DIM    512
#define B_DIM    64
#define L_DIM    2048
#define NBLK1    256       // phase-1 blocks; 1/CU (132 KiB LDS)
#define THREADS1 512
#define MAXCHUNK 512
#define XSZ      (B_DIM * D_DIM)          // 32768 floats per partial

// Native clang vector type (required by __builtin_nontemporal_store).
typedef float f32x4 __attribute__((ext_vector_type(4)));

// ---------------------------------------------------------------------------
// Phase 1: per-block segment-sum into a [B, D] LDS accumulator.
// KEY FIX vs R5: NO LDS atomics. Measured fact (R1/R4/R5 all ~526 us with
// 6256 atomic wave-ops/CU): LDS atomicAdd costs ~200 cyc of serialized LDS
// pipe time on gfx950. Thread tid exclusively owns column tid, so plain
// ds_read / v_add / ds_write (~6 cyc issue) is race-free. The one hazard --
// a node whose two positions coincide (P=1/64) -- is handled by reading both
// slots under one lgkm wait and adding 2v on the second write (write order
// a-then-b makes the duplicate case come out to old+2v).
// ---------------------------------------------------------------------------
__device__ __forceinline__ void rmw2(float* acc, int ia, int ib, float v) {
    float ra = acc[ia];
    float rb = acc[ib];
    float addb = (ia == ib) ? (v + v) : v;
    acc[ia] = ra + v;      // if ia==ib this write is superseded by the next
    acc[ib] = rb + addb;
}

__global__ __launch_bounds__(THREADS1)
void seg_sum_kernel(const float* __restrict__ g, const int* __restrict__ tp,
                    float* __restrict__ dst, int N, int chunk, int use_atomic) {
    __shared__ float acc[XSZ];             // 128 KiB
    __shared__ int   pos[2 * MAXCHUNK];    // 4 KiB
    const int tid = threadIdx.x;

    for (int i = tid; i < XSZ; i += THREADS1) acc[i] = 0.0f;

    int start = blockIdx.x * chunk;
    int end   = start + chunk; if (end > N) end = N;
    int n     = end - start;
    for (int i = tid; i < 2 * n; i += THREADS1) pos[i] = tp[2 * start + i];
    __syncthreads();

    const float* gp = g + (size_t)start * D_DIM + tid;

    int i = 0;
    for (; i + 8 <= n; i += 8) {
        // 8 independent 256 B loads in flight per wave (16 KB/CU at 8 waves).
        float v0 = gp[(size_t)(i + 0) * D_DIM];
        float v1 = gp[(size_t)(i + 1) * D_DIM];
        float v2 = gp[(size_t)(i + 2) * D_DIM];
        float v3 = gp[(size_t)(i + 3) * D_DIM];
        float v4 = gp[(size_t)(i + 4) * D_DIM];
        float v5 = gp[(size_t)(i + 5) * D_DIM];
        float v6 = gp[(size_t)(i + 6) * D_DIM];
        float v7 = gp[(size_t)(i + 7) * D_DIM];
        rmw2(acc, pos[2*i+ 0] * D_DIM + tid, pos[2*i+ 1] * D_DIM + tid, v0);
        rmw2(acc, pos[2*i+ 2] * D_DIM + tid, pos[2*i+ 3] * D_DIM + tid, v1);
        rmw2(acc, pos[2*i+ 4] * D_DIM + tid, pos[2*i+ 5] * D_DIM + tid, v2);
        rmw2(acc, pos[2*i+ 6] * D_DIM + tid, pos[2*i+ 7] * D_DIM + tid, v3);
        rmw2(acc, pos[2*i+ 8] * D_DIM + tid, pos[2*i+ 9] * D_DIM + tid, v4);
        rmw2(acc, pos[2*i+10] * D_DIM + tid, pos[2*i+11] * D_DIM + tid, v5);
        rmw2(acc, pos[2*i+12] * D_DIM + tid, pos[2*i+13] * D_DIM + tid, v6);
        rmw2(acc, pos[2*i+14] * D_DIM + tid, pos[2*i+15] * D_DIM + tid, v7);
    }
    for (; i < n; ++i) {
        float v = gp[(size_t)i * D_DIM];
        rmw2(acc, pos[2*i + 0] * D_DIM + tid, pos[2*i + 1] * D_DIM + tid, v);
    }
    __syncthreads();

    if (use_atomic) {
        for (int j = tid; j < XSZ; j += THREADS1) {
            float v = acc[j];
            if (v != 0.0f) atomicAdd(&dst[j], v);
        }
    } else {
        // Plain coalesced float4 stores of this block's partial.
        f32x4* outp = (f32x4*)(dst + (size_t)blockIdx.x * XSZ);
        const f32x4* a4 = (const f32x4*)acc;
        for (int j = tid; j < XSZ / 4; j += THREADS1) outp[j] = a4[j];
    }
}

// ---------------------------------------------------------------------------
// Reduce 256 per-block partials -> x [B, D]. 33.5 MB of reads, mostly L2
// (partials were just written). 256 blocks x 128 threads.
// ---------------------------------------------------------------------------
__global__ __launch_bounds__(128)
void reduce_partials(const float* __restrict__ p, float* __restrict__ x) {
    int j = blockIdx.x * 128 + threadIdx.x;     // 0..32767
    const float* pj = p + j;
    float s = 0.0f;
    #pragma unroll 8
    for (int k = 0; k < NBLK1; ++k) s += pj[(size_t)k * XSZ];
    x[j] = s;
}

// ---------------------------------------------------------------------------
// Phase 2: broadcast x [B, D] -> out [B, L, D]. Each wave owns one contiguous
// 64 KB span (32 l-rows of one b) and streams sequential 1 KB wave-stores.
// 1024 blocks x 4 waves = 4096 spans.
// ---------------------------------------------------------------------------
#define BC_BLOCKS  1024
#define BC_THREADS 256
__global__ __launch_bounds__(BC_THREADS)
void bcast_lin(const float* __restrict__ x, f32x4* __restrict__ out) {
    int gw   = (blockIdx.x * BC_THREADS + threadIdx.x) >> 6;  // global wave 0..4095
    int lane = threadIdx.x & 63;
    size_t base = (size_t)gw * 4096;          // float4 units; span = 64 KB
    int b = (int)(base >> 18);                // 2^18 float4s per b

    const f32x4* x4 = (const f32x4*)x;
    f32x4 v0 = x4[(b << 7) | lane];
    f32x4 v1 = x4[(b << 7) | (64 + lane)];

    f32x4* o = out + base + lane;
    #pragma unroll 8
    for (int t = 0; t < 64; t += 2) {
        __builtin_nontemporal_store(v0, &o[(size_t)t * 64]);
        __builtin_nontemporal_store(v1, &o[(size_t)t * 64 + 64]);
    }
}

extern "C" void kernel_launch(void* const* d_in, const int* in_sizes, int n_in,
                              void* d_out, int out_size, void* d_ws, size_t ws_size,
                              hipStream_t stream) {
    const float* g   = (const float*)d_in[0];
    const int*   tp  = (const int*)d_in[1];
    float*       out = (float*)d_out;

    int N = in_sizes[1] / 2;               // 100000
    int chunk = (N + NBLK1 - 1) / NBLK1;   // 391 <= MAXCHUNK

    const size_t need = (size_t)(NBLK1 + 1) * XSZ * sizeof(float);  // 33.7 MB

    if (ws_size >= need) {
        float* partials = (float*)d_ws;                    // [256][32768]
        float* x        = partials + (size_t)NBLK1 * XSZ;  // [64][512]
        seg_sum_kernel<<<NBLK1, THREADS1, 0, stream>>>(g, tp, partials, N, chunk, 0);
        reduce_partials<<<XSZ / 128, 128, 0, stream>>>(partials, x);
        bcast_lin<<<BC_BLOCKS, BC_THREADS, 0, stream>>>(x, (f32x4*)out);
    } else {
        // Fallback: atomic flush into x (d_ws poisoned 0xAA -> zero it first).
        float* x = (float*)d_ws;
        (void)hipMemsetAsync(d_ws, 0, XSZ * sizeof(float), stream);
        seg_sum_kernel<<<NBLK1, THREADS1, 0, stream>>>(g, tp, x, N, chunk, 1);
        bcast_lin<<<BC_BLOCKS, BC_THREADS, 0, stream>>>(x, (f32x4*)out);
    }
}